// Round 3
// baseline (1633.048 us; speedup 1.0000x reference)
//
#include <hip/hip_runtime.h>

// ChainMessagePassing: out[n] = sum over edges with dst==n of x[src], over two edge lists.
// x: [N=100000, 64] fp32; indices: [2, E=3200000] (src row 0, dst row 1), int64 or int32.
//
// R6b: R6 with compile fix (nontemporal store needs a native ext_vector type,
// not HIP_vector_type float4). Pipeline rationale unchanged:
//  (a) scatter: plain stores (L2 write-combines runs); R5's nt-store made every
//      random 4B store a full-line HBM write (WRITE_SIZE 391MB, 620us).
//  (b) gather: x (25.6MB) > 4MB per-XCD L2 caused 27x refetch (686MB FETCH,
//      3.4TB/s L3 plateau). Slice x into 8 column slices of 32B/row (3.2MB,
//      L2-resident) and pin slice s to XCD s via blockIdx&7 (round-robin
//      dispatch heuristic; perf-only). 2-lane teams per node, 128 nodes/block.
//      srcs read nontemporal (streamed, don't evict x); out stored nontemporal.

static constexpr int D = 64;
static constexpr int Q = 16;           // float4 quads per row
static constexpr int SB = 256;         // scan blocks (must equal scan block dim)
static constexpr int NPB2 = 128;       // nodes per gather block (2 lanes/node)
static constexpr int NSLICE = 8;       // column slices (= XCDs), 32B each

typedef float v4f __attribute__((ext_vector_type(4)));

// ---- index dtype sniffer: int64 nonneg <2^31 has all-zero odd dwords ----
__global__ void detect_idx_dtype(const int* __restrict__ w, int* __restrict__ flag) {
    int tid = threadIdx.x;  // one wave
    int v = w[2 * tid + 1];
    unsigned long long m = __ballot(v != 0);
    if (tid == 0) *flag = (m == 0ULL) ? 1 : 0;
}

__device__ __forceinline__ int load_idx(const void* idx, long long i, int is64) {
    return is64 ? (int)((const long long*)idx)[i] : ((const int*)idx)[i];
}

// ---- phase 1: per-node degree histogram, direct global atomics (fire-and-forget) ----
__global__ __launch_bounds__(256) void hist_kernel(
        const void* __restrict__ up, const void* __restrict__ down,
        int* __restrict__ counts, const int* __restrict__ flag, int E) {
    const int is64 = *flag;
    const long long total = 2LL * E;
    const long long nq = (total + 3) >> 2;
    const long long stride = (long long)gridDim.x * blockDim.x;
    for (long long t = (long long)blockIdx.x * blockDim.x + threadIdx.x;
         t < nq; t += stride) {
        const long long e0 = t << 2;
        #pragma unroll
        for (int k = 0; k < 4; k++) {
            long long e = e0 + k;
            if (e < total) {
                const void* idx = up; long long ee = e;
                if (ee >= E) { idx = down; ee -= E; }
                int dst = load_idx(idx, E + ee, is64);
                atomicAdd(&counts[dst], 1);
            }
        }
    }
}

// ---- phase 2a: per-block partial sums over counts ----
__global__ __launch_bounds__(256) void scan_partials_kernel(
        const int* __restrict__ counts, int* __restrict__ partials,
        int N, int cpt) {
    __shared__ int red[256];
    const int blk = blockIdx.x, tid = threadIdx.x;
    const long long base = (long long)(blk * 256 + tid) * cpt;
    int s = 0;
    for (int k = 0; k < cpt; k++) {
        long long i = base + k;
        if (i < N) s += counts[i];
    }
    red[tid] = s;
    __syncthreads();
    for (int off = 128; off > 0; off >>= 1) {
        if (tid < off) red[tid] += red[tid + off];
        __syncthreads();
    }
    if (tid == 0) partials[blk] = red[0];
}

// ---- phase 2b: apply — per-block base from partials, block scan, write offsets+cursors ----
__global__ __launch_bounds__(256) void scan_apply_kernel(
        const int* __restrict__ counts, const int* __restrict__ partials,
        int* __restrict__ offsets, int* __restrict__ cursors,
        int N, int cpt, int total) {
    __shared__ int sh[256];
    const int blk = blockIdx.x, tid = threadIdx.x;
    sh[tid] = (tid < blk) ? partials[tid] : 0;   // SB == 256 == blockDim
    __syncthreads();
    for (int off = 128; off > 0; off >>= 1) {
        if (tid < off) sh[tid] += sh[tid + off];
        __syncthreads();
    }
    const int bbase = sh[0];
    __syncthreads();
    const long long base = (long long)(blk * 256 + tid) * cpt;
    int s = 0;
    for (int k = 0; k < cpt; k++) {
        long long i = base + k;
        if (i < N) s += counts[i];
    }
    sh[tid] = s;
    __syncthreads();
    for (int off = 1; off < 256; off <<= 1) {
        int t = (tid >= off) ? sh[tid - off] : 0;
        __syncthreads();
        sh[tid] += t;
        __syncthreads();
    }
    int run = bbase + ((tid == 0) ? 0 : sh[tid - 1]);
    for (int k = 0; k < cpt; k++) {
        long long i = base + k;
        if (i < N) {
            int c = counts[i];
            offsets[i] = run;
            cursors[i] = run;
            run += c;
        }
    }
    if (blk == 0 && tid == 0) offsets[N] = total;
}

// ---- phase 3: single-pass scatter of src into per-node runs ----
// Plain stores (L2 write-combines consecutive positions of each node's run);
// 4 edges/thread/iter for atomic-return MLP.
__global__ __launch_bounds__(256) void scatter_kernel(
        const void* __restrict__ up, const void* __restrict__ down,
        int* __restrict__ cursors, int* __restrict__ srcbuf,
        const int* __restrict__ flag, int E) {
    const int is64 = *flag;
    const long long total = 2LL * E;
    const long long nq = (total + 3) >> 2;
    const long long stride = (long long)gridDim.x * blockDim.x;
    for (long long t = (long long)blockIdx.x * blockDim.x + threadIdx.x;
         t < nq; t += stride) {
        const long long e0 = t << 2;
        int srcs[4], dsts[4];
        int nk = 0;
        #pragma unroll
        for (int k = 0; k < 4; k++) {
            long long e = e0 + k;
            if (e < total) {
                const void* idx = up; long long ee = e;
                if (ee >= E) { idx = down; ee -= E; }
                srcs[nk] = load_idx(idx, ee, is64);
                dsts[nk] = load_idx(idx, E + ee, is64);
                nk++;
            }
        }
        #pragma unroll
        for (int k = 0; k < 4; k++) {
            if (k < nk) {
                int pos = atomicAdd(&cursors[dsts[k]], 1);
                srcbuf[pos] = srcs[k];
            }
        }
    }
}

// ---- phase 4: XCD-sliced pure gather ----
// slice = blockIdx&7 -> 32B column slice [slice*8, slice*8+8) of every row;
// slice footprint of x = N*32B = 3.2MB, L2-resident on its XCD (blockIdx&7
// round-robin). 2-lane teams per node (2 x float4), 128 nodes per block.
__global__ __launch_bounds__(256) void gather_kernel(
        const float* __restrict__ x, const int* __restrict__ offsets,
        const int* __restrict__ srcs, float* __restrict__ out, int N) {
    const int slice = blockIdx.x & (NSLICE - 1);
    const int chunk = blockIdx.x >> 3;
    const int tid = threadIdx.x;
    const int team = tid >> 1;        // 0..127
    const int half = tid & 1;         // float4 within 32B slice
    const int node = chunk * NPB2 + team;
    if (node >= N) return;

    const int col = slice * 8 + half * 4;     // float offset in row
    const float* xq = x + col;

    const int rb = offsets[node];
    const int re = offsets[node + 1];
    float4 acc = make_float4(0.f, 0.f, 0.f, 0.f);
    int e = rb;
    for (; e + 8 <= re; e += 8) {  // 8 row-gathers in flight
        const int s0 = __builtin_nontemporal_load(srcs + e + 0);
        const int s1 = __builtin_nontemporal_load(srcs + e + 1);
        const int s2 = __builtin_nontemporal_load(srcs + e + 2);
        const int s3 = __builtin_nontemporal_load(srcs + e + 3);
        const int s4 = __builtin_nontemporal_load(srcs + e + 4);
        const int s5 = __builtin_nontemporal_load(srcs + e + 5);
        const int s6 = __builtin_nontemporal_load(srcs + e + 6);
        const int s7 = __builtin_nontemporal_load(srcs + e + 7);
        const float4 v0 = *(const float4*)(xq + (long long)s0 * D);
        const float4 v1 = *(const float4*)(xq + (long long)s1 * D);
        const float4 v2 = *(const float4*)(xq + (long long)s2 * D);
        const float4 v3 = *(const float4*)(xq + (long long)s3 * D);
        const float4 v4 = *(const float4*)(xq + (long long)s4 * D);
        const float4 v5 = *(const float4*)(xq + (long long)s5 * D);
        const float4 v6 = *(const float4*)(xq + (long long)s6 * D);
        const float4 v7 = *(const float4*)(xq + (long long)s7 * D);
        acc.x += ((v0.x + v1.x) + (v2.x + v3.x)) + ((v4.x + v5.x) + (v6.x + v7.x));
        acc.y += ((v0.y + v1.y) + (v2.y + v3.y)) + ((v4.y + v5.y) + (v6.y + v7.y));
        acc.z += ((v0.z + v1.z) + (v2.z + v3.z)) + ((v4.z + v5.z) + (v6.z + v7.z));
        acc.w += ((v0.w + v1.w) + (v2.w + v3.w)) + ((v4.w + v5.w) + (v6.w + v7.w));
    }
    for (; e < re; e++) {
        const int s = __builtin_nontemporal_load(srcs + e);
        const float4 v = *(const float4*)(xq + (long long)s * D);
        acc.x += v.x; acc.y += v.y; acc.z += v.z; acc.w += v.w;
    }
    v4f accv = { acc.x, acc.y, acc.z, acc.w };
    __builtin_nontemporal_store(accv, (v4f*)(out + (long long)node * D + col));
}

// ---- fallback: direct fp32 atomics (R1), needs no workspace ----
__global__ __launch_bounds__(256) void scatter_add_kernel(
        const float* __restrict__ x, const void* __restrict__ up_idx,
        const void* __restrict__ down_idx, float* __restrict__ out,
        const int* __restrict__ dtype_flag, int num_edges) {
    const int is64 = *dtype_flag;
    const long long total = 2LL * num_edges * Q;
    const long long stride = (long long)gridDim.x * blockDim.x;
    for (long long t = (long long)blockIdx.x * blockDim.x + threadIdx.x;
         t < total; t += stride) {
        const int quad = (int)(t & (Q - 1));
        long long eg = t >> 4;
        const void* idx = up_idx;
        if (eg >= num_edges) { idx = down_idx; eg -= num_edges; }
        int src = load_idx(idx, eg, is64);
        int dst = load_idx(idx, num_edges + eg, is64);
        const float4 v = *(const float4*)(x + (long long)src * D + quad * 4);
        float* o = out + (long long)dst * D + quad * 4;
        unsafeAtomicAdd(o + 0, v.x);
        unsafeAtomicAdd(o + 1, v.y);
        unsafeAtomicAdd(o + 2, v.z);
        unsafeAtomicAdd(o + 3, v.w);
    }
}

extern "C" void kernel_launch(void* const* d_in, const int* in_sizes, int n_in,
                              void* d_out, int out_size, void* d_ws, size_t ws_size,
                              hipStream_t stream) {
    const float* x = (const float*)d_in[0];
    const void* up_idx = d_in[1];
    const void* down_idx = d_in[2];
    float* out = (float*)d_out;

    const int E = in_sizes[1] / 2;   // [2, E]
    const int N = out_size / D;      // [N, 64]
    const long long Etot = 2LL * E;

    // ws layout (ints): flag(64) | counts[N] | offsets[N+16] | cursors[N] | partials[320] | srcbuf[2E]
    int* ws_i = (int*)d_ws;
    int* flag = ws_i;
    int* counts = ws_i + 64;
    int* offsets = counts + N;
    int* cursors = offsets + N + 16;
    int* partials = cursors + N;
    int* srcbuf = partials + 320;
    const size_t ws_need = ((size_t)64 + 3LL * N + 16 + 320 + (size_t)Etot) * 4 + 64;

    detect_idx_dtype<<<1, 64, 0, stream>>>((const int*)up_idx, flag);

    if (ws_size >= ws_need && Etot < (1LL << 31) && N >= 1) {
        hipMemsetAsync(counts, 0, (size_t)N * sizeof(int), stream);
        hist_kernel<<<2048, 256, 0, stream>>>(up_idx, down_idx, counts, flag, E);
        const int cpt = (N + SB * 256 - 1) / (SB * 256);
        scan_partials_kernel<<<SB, 256, 0, stream>>>(counts, partials, N, cpt);
        scan_apply_kernel<<<SB, 256, 0, stream>>>(counts, partials, offsets, cursors,
                                                  N, cpt, (int)Etot);
        scatter_kernel<<<2048, 256, 0, stream>>>(up_idx, down_idx, cursors, srcbuf,
                                                 flag, E);
        const int cpb = (N + NPB2 - 1) / NPB2;
        gather_kernel<<<NSLICE * cpb, 256, 0, stream>>>(x, offsets, srcbuf, out, N);
    } else {
        hipMemsetAsync(d_out, 0, (size_t)out_size * sizeof(float), stream);
        scatter_add_kernel<<<8192, 256, 0, stream>>>(x, up_idx, down_idx, out, flag, E);
    }
}

// Round 4
// 1054.123 us; speedup vs baseline: 1.5492x; 1.5492x over previous
//
#include <hip/hip_runtime.h>

// ChainMessagePassing: out[n] = sum over edges with dst==n of x[src], over two edge lists.
// x: [N=100000, 64] fp32; indices: [2, E=3200000] (src row 0, dst row 1), int64 or int32.
//
// R7: temporal src-tiling. R6b's spatial XCD-pinning (blockIdx&7) failed: FETCH
// 2.86GB (every 32B slice read missed L2 - dispatch doesn't keep slices on one
// XCD). Both R4 (686MB/215us) and R6b (2.86GB/795us) sit at ~3.4-3.7 TB/s of
// L2-fill bandwidth -> that's the fabric/L3 ceiling; the lever is FETCH_SIZE.
// Fix: CSR keys = dst*NT + (src>>SHIFT), tiles of 8192 rows (2MB < 4MB L2).
// Gather blocks (64 nodes, 16-lane full-row teams, all co-resident) sweep src
// tiles in lockstep-ish time order, so the chip-wide x working set at any
// instant is ~1 tile and every XCD's L2 holds it. Expected x fill ~205MB.
// In-place scan (one keys array: counts -> exclusive offsets -> post-scatter
// inclusive ends) keeps ws ~31MB; shift auto-coarsens if ws is tight.

static constexpr int D = 64;
static constexpr int Q = 16;           // float4 quads per row
static constexpr int SB = 256;         // scan blocks (== scan block dim)

typedef float v4f __attribute__((ext_vector_type(4)));

// ---- index dtype sniffer: int64 nonneg <2^31 has all-zero odd dwords ----
__global__ void detect_idx_dtype(const int* __restrict__ w, int* __restrict__ flag) {
    int tid = threadIdx.x;  // one wave
    int v = w[2 * tid + 1];
    unsigned long long m = __ballot(v != 0);
    if (tid == 0) *flag = (m == 0ULL) ? 1 : 0;
}

__device__ __forceinline__ int load_idx_nt(const void* idx, long long i, int is64) {
    return is64 ? (int)__builtin_nontemporal_load(((const long long*)idx) + i)
                : __builtin_nontemporal_load(((const int*)idx) + i);
}

// ---- phase 1: histogram over (dst,tile) keys, direct global atomics ----
__global__ __launch_bounds__(256) void hist_kernel(
        const void* __restrict__ up, const void* __restrict__ down,
        int* __restrict__ keys, const int* __restrict__ flag, int E,
        int shift, int NT) {
    const int is64 = *flag;
    const long long total = 2LL * E;
    const long long ng = (total + 7) >> 3;
    const long long stride = (long long)gridDim.x * blockDim.x;
    for (long long t = (long long)blockIdx.x * blockDim.x + threadIdx.x;
         t < ng; t += stride) {
        const long long e0 = t << 3;
        #pragma unroll
        for (int k = 0; k < 8; k++) {
            long long e = e0 + k;
            if (e < total) {
                const void* idx = up; long long ee = e;
                if (ee >= E) { idx = down; ee -= E; }
                int src = load_idx_nt(idx, ee, is64);
                int dst = load_idx_nt(idx, E + ee, is64);
                atomicAdd(&keys[dst * NT + (src >> shift)], 1);
            }
        }
    }
}

// ---- phase 2a: per-block partial sums ----
__global__ __launch_bounds__(256) void scan_partials_kernel(
        const int* __restrict__ keys, int* __restrict__ partials,
        int bins, int cpt) {
    __shared__ int red[256];
    const int blk = blockIdx.x, tid = threadIdx.x;
    const long long base = (long long)(blk * 256 + tid) * cpt;
    int s = 0;
    for (int k = 0; k < cpt; k++) {
        long long i = base + k;
        if (i < bins) s += keys[i];
    }
    red[tid] = s;
    __syncthreads();
    for (int off = 128; off > 0; off >>= 1) {
        if (tid < off) red[tid] += red[tid + off];
        __syncthreads();
    }
    if (tid == 0) partials[blk] = red[0];
}

// ---- phase 2b: in-place exclusive scan (keys: counts -> exclusive offsets) ----
__global__ __launch_bounds__(256) void scan_apply_kernel(
        int* __restrict__ keys, const int* __restrict__ partials,
        int bins, int cpt) {
    __shared__ int sh[256];
    const int blk = blockIdx.x, tid = threadIdx.x;
    sh[tid] = (tid < blk) ? partials[tid] : 0;   // SB == 256 == blockDim
    __syncthreads();
    for (int off = 128; off > 0; off >>= 1) {
        if (tid < off) sh[tid] += sh[tid + off];
        __syncthreads();
    }
    const int bbase = sh[0];
    __syncthreads();
    const long long base = (long long)(blk * 256 + tid) * cpt;
    int s = 0;
    for (int k = 0; k < cpt; k++) {
        long long i = base + k;
        if (i < bins) s += keys[i];
    }
    sh[tid] = s;
    __syncthreads();
    for (int off = 1; off < 256; off <<= 1) {
        int t = (tid >= off) ? sh[tid - off] : 0;
        __syncthreads();
        sh[tid] += t;
        __syncthreads();
    }
    int run = bbase + ((tid == 0) ? 0 : sh[tid - 1]);
    for (int k = 0; k < cpt; k++) {
        long long i = base + k;
        if (i < bins) {
            int c = keys[i];
            keys[i] = run;      // in-place: exclusive offset
            run += c;
        }
    }
}

// ---- phase 3: scatter src into (dst,tile) runs; keys become inclusive ends ----
__global__ __launch_bounds__(256) void scatter_kernel(
        const void* __restrict__ up, const void* __restrict__ down,
        int* __restrict__ keys, int* __restrict__ srcbuf,
        const int* __restrict__ flag, int E, int shift, int NT) {
    const int is64 = *flag;
    const long long total = 2LL * E;
    const long long ng = (total + 7) >> 3;
    const long long stride = (long long)gridDim.x * blockDim.x;
    for (long long t = (long long)blockIdx.x * blockDim.x + threadIdx.x;
         t < ng; t += stride) {
        const long long e0 = t << 3;
        int srcs[8], ks[8];
        int nk = 0;
        #pragma unroll
        for (int k = 0; k < 8; k++) {
            long long e = e0 + k;
            if (e < total) {
                const void* idx = up; long long ee = e;
                if (ee >= E) { idx = down; ee -= E; }
                int src = load_idx_nt(idx, ee, is64);
                int dst = load_idx_nt(idx, E + ee, is64);
                srcs[nk] = src;
                ks[nk] = dst * NT + (src >> shift);
                nk++;
            }
        }
        #pragma unroll
        for (int k = 0; k < 8; k++) {
            if (k < nk) {
                int pos = atomicAdd(&keys[ks[k]], 1);
                srcbuf[pos] = srcs[k];
            }
        }
    }
}

// ---- phase 4: tiled gather. 16 lanes/node (full 256B row), 4 nodes/team,
// 64 nodes/block, all blocks co-resident; outer loop over src tiles keeps the
// chip-wide x working set at ~1 tile (2MB) -> L2-resident on every XCD. ----
__global__ __launch_bounds__(256, 8) void gather_kernel(
        const float* __restrict__ x, const int* __restrict__ keys,
        const int* __restrict__ srcs, float* __restrict__ out,
        int N, int NT) {
    const int tid = threadIdx.x;
    const int team = tid >> 4;        // 0..15
    const int q = tid & 15;           // float4 quad within row
    const int base_node = blockIdx.x * 64 + team * 4;
    const float* xq = x + q * 4;

    float4 acc[4];
    int rb[4];
    #pragma unroll
    for (int j = 0; j < 4; j++) {
        acc[j] = make_float4(0.f, 0.f, 0.f, 0.f);
        const int node = base_node + j;
        rb[j] = (node <= 0 || node >= N) ? 0 : keys[node * NT - 1];
    }

    for (int t = 0; t < NT; t++) {
        #pragma unroll
        for (int j = 0; j < 4; j++) {
            const int node = base_node + j;
            if (node < N) {
                const int re = keys[node * NT + t];   // inclusive end of (node,t)
                int e = rb[j];
                rb[j] = re;
                for (; e + 4 <= re; e += 4) {
                    const int s0 = __builtin_nontemporal_load(srcs + e + 0);
                    const int s1 = __builtin_nontemporal_load(srcs + e + 1);
                    const int s2 = __builtin_nontemporal_load(srcs + e + 2);
                    const int s3 = __builtin_nontemporal_load(srcs + e + 3);
                    const float4 v0 = *(const float4*)(xq + (long long)s0 * D);
                    const float4 v1 = *(const float4*)(xq + (long long)s1 * D);
                    const float4 v2 = *(const float4*)(xq + (long long)s2 * D);
                    const float4 v3 = *(const float4*)(xq + (long long)s3 * D);
                    acc[j].x += (v0.x + v1.x) + (v2.x + v3.x);
                    acc[j].y += (v0.y + v1.y) + (v2.y + v3.y);
                    acc[j].z += (v0.z + v1.z) + (v2.z + v3.z);
                    acc[j].w += (v0.w + v1.w) + (v2.w + v3.w);
                }
                for (; e < re; e++) {
                    const int s = __builtin_nontemporal_load(srcs + e);
                    const float4 v = *(const float4*)(xq + (long long)s * D);
                    acc[j].x += v.x; acc[j].y += v.y; acc[j].z += v.z; acc[j].w += v.w;
                }
            }
        }
        __syncthreads();   // keep block's teams on the same tile
    }

    #pragma unroll
    for (int j = 0; j < 4; j++) {
        const int node = base_node + j;
        if (node < N) {
            v4f a = { acc[j].x, acc[j].y, acc[j].z, acc[j].w };
            __builtin_nontemporal_store(a, (v4f*)(out + (long long)node * D + q * 4));
        }
    }
}

// ---- fallback: direct fp32 atomics (R1), needs no workspace ----
__global__ __launch_bounds__(256) void scatter_add_kernel(
        const float* __restrict__ x, const void* __restrict__ up_idx,
        const void* __restrict__ down_idx, float* __restrict__ out,
        const int* __restrict__ dtype_flag, int num_edges) {
    const int is64 = *dtype_flag;
    const long long total = 2LL * num_edges * Q;
    const long long stride = (long long)gridDim.x * blockDim.x;
    for (long long t = (long long)blockIdx.x * blockDim.x + threadIdx.x;
         t < total; t += stride) {
        const int quad = (int)(t & (Q - 1));
        long long eg = t >> 4;
        const void* idx = up_idx;
        if (eg >= num_edges) { idx = down_idx; eg -= num_edges; }
        int src = load_idx_nt(idx, eg, is64);
        int dst = load_idx_nt(idx, num_edges + eg, is64);
        const float4 v = *(const float4*)(x + (long long)src * D + quad * 4);
        float* o = out + (long long)dst * D + quad * 4;
        unsafeAtomicAdd(o + 0, v.x);
        unsafeAtomicAdd(o + 1, v.y);
        unsafeAtomicAdd(o + 2, v.z);
        unsafeAtomicAdd(o + 3, v.w);
    }
}

extern "C" void kernel_launch(void* const* d_in, const int* in_sizes, int n_in,
                              void* d_out, int out_size, void* d_ws, size_t ws_size,
                              hipStream_t stream) {
    const float* x = (const float*)d_in[0];
    const void* up_idx = d_in[1];
    const void* down_idx = d_in[2];
    float* out = (float*)d_out;

    const int E = in_sizes[1] / 2;   // [2, E]
    const int N = out_size / D;      // [N, 64]
    const long long Etot = 2LL * E;

    // pick tile shift: finest that fits ws (tiles of 2^shift rows)
    int shift = 13;
    long long bins = 0;
    size_t ws_need = (size_t)-1;
    while (true) {
        int nt = (int)(((long long)(N - 1) >> shift) + 1);
        bins = (long long)N * nt;
        ws_need = ((size_t)64 + (size_t)bins + 320 + (size_t)Etot) * 4 + 64;
        if ((ws_need <= ws_size && bins < (1LL << 31)) || shift >= 24) break;
        shift++;
    }
    const int NT = (int)(((long long)(N - 1) >> shift) + 1);

    // ws layout (ints): flag(64) | keys[bins] | partials[320] | srcbuf[Etot]
    int* ws_i = (int*)d_ws;
    int* flag = ws_i;
    int* keys = ws_i + 64;
    int* partials = keys + bins;
    int* srcbuf = partials + 320;

    detect_idx_dtype<<<1, 64, 0, stream>>>((const int*)up_idx, flag);

    if (ws_size >= ws_need && Etot < (1LL << 31) && bins < (1LL << 31) && N >= 1) {
        hipMemsetAsync(keys, 0, (size_t)bins * sizeof(int), stream);
        hist_kernel<<<2048, 256, 0, stream>>>(up_idx, down_idx, keys, flag, E, shift, NT);
        const int cpt = (int)((bins + SB * 256 - 1) / (SB * 256));
        scan_partials_kernel<<<SB, 256, 0, stream>>>(keys, partials, (int)bins, cpt);
        scan_apply_kernel<<<SB, 256, 0, stream>>>(keys, partials, (int)bins, cpt);
        scatter_kernel<<<2048, 256, 0, stream>>>(up_idx, down_idx, keys, srcbuf,
                                                 flag, E, shift, NT);
        gather_kernel<<<(N + 63) / 64, 256, 0, stream>>>(x, keys, srcbuf, out, N, NT);
    } else {
        hipMemsetAsync(d_out, 0, (size_t)out_size * sizeof(float), stream);
        scatter_add_kernel<<<8192, 256, 0, stream>>>(x, up_idx, down_idx, out, flag, E);
    }
}